// Round 1
// baseline (184.364 us; speedup 1.0000x reference)
//
#include <hip/hip_runtime.h>
#include <stdint.h>

typedef unsigned int u32;
typedef unsigned long long u64;

#define N_ITEMS 131072
#define NB 131072                   // buckets (monotone in descending score)
#define NSLICE 4                    // XCD-sliced histogram copies
#define MBLK 64                     // fused scan/pav/merge blocks
#define BUCK_PER_BLK 2048           // buckets per fused block
#define CH_PER_BLK 32               // chunks (64 buckets) per fused block
#define PAD 65                      // padded LDS record stride per chunk
#define REGSLOT 2048                // record slots per region in global REC
#define FIXSCALE 268435456.0f       // 2^28 fixed-point scale for sum(exp)
#define FIXMASK ((1ull << 46) - 1)

// ---------- helpers ----------

// sum_{i=s}^{e} (N - i) — exact weight-side sum of exp(w) over sorted positions
__device__ __forceinline__ float wsumf(int s, int e) {
  return 0.5f * (float)(e - s + 1) * (float)(2 * N_ITEMS - s - e);
}

__device__ __forceinline__ float key_to_score(u32 key) {
  u32 m = ~key;
  u32 u = (m & 0x80000000u) ? (m ^ 0x80000000u) : ~m;
  return __uint_as_float(u);
}

#define LOG2E 1.4426950408889634f
__device__ __forceinline__ float fexp(float x) { return exp2f(x * LOG2E); }

// ascending key == descending score; ascending bucket == descending score
__device__ __forceinline__ u32 bucket_of(u32 key, u32 kmin, u32 kmax) {
  double scale = (double)NB / ((double)(kmax - kmin) + 1.0);
  u32 b = (u32)((double)(key - kmin) * scale);
  return b < NB ? b : (NB - 1);
}

__device__ __forceinline__ float recSY(int2 r) { return __int_as_float(r.y); }

// ---------- 1) fused: scores -> keys -> grid barrier -> global minmax -> hist ----------
// 512 blocks x 256 threads: all co-resident (capacity 2048 blocks at 4 waves/blk).
// Release/acquire: plain stores -> __threadfence -> atomic arrive; spin -> __threadfence.

__global__ __launch_bounds__(256) void score_hist_kernel(
    const float* __restrict__ x,
    const float* __restrict__ w1, const float* __restrict__ b1,
    const float* __restrict__ w2, const float* __restrict__ b2,
    u32* __restrict__ keyRaw, u32* __restrict__ pmin, u32* __restrict__ pmax,
    u32* __restrict__ done, u64* __restrict__ hist8, u32* __restrict__ mm) {
  __shared__ u32 r0[256], r1[256];
  int t = threadIdx.x;
  int i = blockIdx.x * 256 + t;
  float xv = x[i];
  float s = b2[0];
#pragma unroll
  for (int j = 0; j < 32; ++j) {
    float h = fmaf(xv, w1[j], b1[j]);
    h = fmaxf(h, 0.0f);
    s = fmaf(h, w2[j], s);
  }
  u32 u = __float_as_uint(s);
  u32 m = u ^ ((u & 0x80000000u) ? 0xFFFFFFFFu : 0x80000000u); // ascending map
  u32 key = ~m;
  keyRaw[i] = key;
  r0[t] = key; r1[t] = key;
  __syncthreads();
  for (int off = 128; off > 0; off >>= 1) {
    if (t < off) { r0[t] = min(r0[t], r0[t + off]); r1[t] = max(r1[t], r1[t + off]); }
    __syncthreads();
  }
  if (t == 0) {
    pmin[blockIdx.x] = r0[0];
    pmax[blockIdx.x] = r1[0];
    __threadfence();                       // release partials
    atomicAdd(done, 1u);                   // arrive
    while (atomicAdd(done, 0u) < 512u) __builtin_amdgcn_s_sleep(2);
  }
  __syncthreads();
  __threadfence();                         // acquire all partials
  // every block reduces the 512 partials (2 MB total L2-hot reads)
  r0[t] = min(pmin[t], pmin[t + 256]);
  r1[t] = max(pmax[t], pmax[t + 256]);
  __syncthreads();
  for (int off = 128; off > 0; off >>= 1) {
    if (t < off) { r0[t] = min(r0[t], r0[t + off]); r1[t] = max(r1[t], r1[t + off]); }
    __syncthreads();
  }
  u32 kmin = r0[0], kmax = r1[0];
  if (blockIdx.x == 0 && t == 0) { mm[0] = kmin; mm[1] = kmax; }
  u32 g = bucket_of(key, kmin, kmax);
  float smax = key_to_score(kmin);
  float v = fexp(key_to_score(key) - smax);            // in (0, 1]
  u64 fix = (u64)fmaxf(1.0f, fmaf(v, FIXSCALE, 0.5f)); // clamp: SY can never be 0
  size_t slice = (size_t)(blockIdx.x & (NSLICE - 1)) * NB;
  atomicAdd(&hist8[slice + g], (1ull << 46) | fix);
}

// ---------- 2) fused: scan + PAV + in-LDS merges + cross-block region tree + out ----------
// 64 blocks x 256. Tree levels 0..5 at region granularity via flag2 release/acquire.
// After block 0 publishes the root, all blocks run the out phase (2048 items each).

__global__ __launch_bounds__(256) void solve_kernel(
    const u64* __restrict__ hist8, u64* __restrict__ flags, u64* __restrict__ flag2,
    u32* __restrict__ cdf, int2* __restrict__ REC,
    const u32* __restrict__ keyRaw, const u32* __restrict__ mm,
    float* __restrict__ out) {
  __shared__ u32 vals[BUCK_PER_BLK + 1];   // counts -> global-exclusive cdf
  __shared__ float seL[BUCK_PER_BLK];
  __shared__ int   rST[CH_PER_BLK * PAD];
  __shared__ float rSY[CH_PER_BLK * PAD];
  __shared__ u32 sh[256];
  __shared__ u32 agg[64];
  __shared__ u32 regS[65];                 // region start positions (global item idx)
  __shared__ int lcnt[CH_PER_BLK];
  __shared__ int ca[16], cb[16], cM[16];
  __shared__ int shInt[4];
  int t = threadIdx.x, b = blockIdx.x;
  int B0 = b * BUCK_PER_BLK;
  // coalesced load + slice reduce
  for (int q = 0; q < 8; ++q) {
    int ii = q * 256 + t;
    u64 acc = 0;
#pragma unroll
    for (int c = 0; c < NSLICE; ++c) acc += hist8[(size_t)c * NB + B0 + ii];
    vals[ii] = (u32)(acc >> 46);
    seL[ii] = (float)(acc & FIXMASK) * (1.0f / FIXSCALE);
  }
  __syncthreads();
  // per-thread local prefix over contiguous 8, then block scan
  u32 loc[8]; u32 s = 0;
  for (int q = 0; q < 8; ++q) { loc[q] = s; s += vals[t * 8 + q]; }
  sh[t] = s;
  __syncthreads();
  for (int off = 1; off < 256; off <<= 1) {
    u32 x2 = (t >= off) ? sh[t - off] : 0u;
    __syncthreads();
    sh[t] += x2;
    __syncthreads();
  }
  // publish aggregate; wait-all over ALL 64 blocks (full prefix needed for the tree)
  if (t == 0) atomicExch(&flags[b], (1ull << 32) | (u64)sh[255]);
  if (t < 64) {
    u64 f;
    do { f = atomicAdd(&flags[t], 0ull); } while ((u32)(f >> 32) == 0u);
    agg[t] = (u32)f;
  }
  __syncthreads();
  if (t < 64) {                 // wave-level exclusive scan over 64 aggregates
    u32 v = agg[t];
    u32 inc = v;
    for (int off = 1; off < 64; off <<= 1) {
      u32 o2 = __shfl_up(inc, off);
      if (t >= off) inc += o2;
    }
    regS[t] = inc - v;
    if (t == 63) regS[64] = inc;          // == N_ITEMS
  }
  __syncthreads();
  u32 exclu = regS[b];
  u32 tbase = ((t == 0) ? 0u : sh[t - 1]) + exclu;
  // overwrite vals with GLOBAL exclusive cdf; mirror to global (vectorized)
  u32 eb8[8];
  for (int q = 0; q < 8; ++q) { eb8[q] = tbase + loc[q]; vals[t * 8 + q] = eb8[q]; }
  {
    uint4* c4 = (uint4*)(cdf + B0 + t * 8);
    c4[0] = make_uint4(eb8[0], eb8[1], eb8[2], eb8[3]);
    c4[1] = make_uint4(eb8[4], eb8[5], eb8[6], eb8[7]);
  }
  if (t == 255) vals[BUCK_PER_BLK] = exclu + sh[255];
  __syncthreads();
  // per-chunk PAV (32 threads), stack stored in place at padded stride
  if (t < CH_PER_BLK) {
    int base = t * PAD;
    int ptr = 0; bool have = false;
    float syT = 0.0f; int stT = 0;
    for (int k = 0; k < 64; ++k) {
      u32 cs = vals[t * 64 + k], ce = vals[t * 64 + k + 1];
      if (ce == cs) continue;                 // empty bucket
      float syC = seL[t * 64 + k];
      int stC = (int)cs, eC = (int)ce - 1;
      while (have) {
        float SWc = wsumf(stC, eC);
        float SWt = wsumf(stT, stC - 1);
        if (!(syT * SWc <= syC * SWt)) break; // merge while val_top <= val_cur
        syC += syT; stC = stT;
        if (ptr == 0) { have = false; break; }
        --ptr;
        stT = rST[base + ptr]; syT = rSY[base + ptr];
      }
      if (have) { rST[base + ptr] = stT; rSY[base + ptr] = syT; ++ptr; }
      stT = stC; syT = syC; have = true;
    }
    if (have) { rST[base + ptr] = stT; rSY[base + ptr] = syT; ++ptr; }
    lcnt[t] = ptr;
  }
  __syncthreads();
  // merge levels 0..4 entirely in LDS; copies wave-parallel across disjoint pairs
  for (int j = 0; j < 5; ++j) {
    int P = CH_PER_BLK >> (j + 1);
    if (t < P) {
      int p = t;
      int kL = p << (j + 1), kR = kL + (1 << j);
      int slotL = kL * PAD, slotR = kR * PAD;
      int nL = lcnt[kL], nR = lcnt[kR];
      int a = 0, bb = 0, hasM = 0;
      if (nL > 0 && nR > 0) {
        int gstartR = (int)vals[kR * 64];
        int gendR   = (int)vals[(kR + (1 << j)) * 64];
        float SYL = rSY[slotL + nL - 1]; int stL = rST[slotL + nL - 1];
        float SYR = rSY[slotR];
        int eR = (nR > 1) ? (rST[slotR + 1] - 1) : (gendR - 1);
        float SWL = wsumf(stL, gstartR - 1);
        float SWR = wsumf(gstartR, eR);
        if (SYL * SWR <= SYR * SWL) {
          hasM = 1;
          float SYM = SYL + SYR; int Ms = stL, Me = eR;
          a = 1; bb = 1;
          for (;;) {
            float SWM = wsumf(Ms, Me);
            if (a < nL) {
              float SYe = rSY[slotL + nL - 1 - a]; int ste = rST[slotL + nL - 1 - a];
              float SWe = wsumf(ste, Ms - 1);
              if (SYe * SWM <= SYM * SWe) { SYM += SYe; Ms = ste; ++a; continue; }
            }
            if (bb < nR) {
              float SYb = rSY[slotR + bb]; int sb = rST[slotR + bb];
              int eb = (bb + 1 < nR) ? (rST[slotR + bb + 1] - 1) : (gendR - 1);
              float SWb = wsumf(sb, eb);
              if (SYM * SWb <= SYb * SWM) { SYM += SYb; Me = eb; ++bb; continue; }
            }
            break;
          }
          rST[slotL + nL - a] = Ms; rSY[slotL + nL - a] = SYM;
        }
      }
      ca[p] = a; cb[p] = bb; cM[p] = hasM;
    }
    __syncthreads();
    {
      int w = t >> 6, lane = t & 63;
      for (int p = w; p < P; p += 4) {      // pairs are disjoint -> waves in parallel
        int kL = p << (j + 1), kR = kL + (1 << j);
        int nL = lcnt[kL], nR = lcnt[kR];
        int a = ca[p], bb = cb[p], hasM = cM[p];
        int destBase = kL * PAD + nL - a + hasM;
        int srcBase = kR * PAD + bb;
        int ncopy = nR - bb;
        for (int off = 0; off < ncopy; off += 64) {  // wave-staged, dest<=src, in order
          int k2 = off + lane; bool act = k2 < ncopy;
          int vt = 0; float vs = 0.f;
          if (act) { vt = rST[srcBase + k2]; vs = rSY[srcBase + k2]; }
          if (act) { rST[destBase + k2] = vt; rSY[destBase + k2] = vs; }
        }
      }
    }
    __syncthreads();
    if (t < P) {
      int p = t; int kL = p << (j + 1), kR = kL + (1 << j);
      lcnt[kL] = lcnt[kL] - ca[p] + cM[p] + (lcnt[kR] - cb[p]);
    }
    __syncthreads();
  }
  // write region records (coalesced)
  int myCnt = lcnt[0];
  for (int k = t; k < myCnt; k += 256)
    REC[(size_t)b * REGSLOT + k] = make_int2(rST[k], __float_as_int(rSY[k]));
  __syncthreads();
  // ---- cross-block region tree, levels 0..5 ----
  int lvl = 0;
  for (;;) {
    if (b & (1 << lvl)) {                  // right child: publish subtree, leave tree
      __threadfence();
      if (t == 0) atomicExch(&flag2[b], (1ull << 32) | (u64)(u32)myCnt);
      break;
    }
    if (lvl == 6) {                        // b == 0: root done
      __threadfence();
      if (t == 0) atomicExch(&flag2[0], (2ull << 32) | (u64)(u32)myCnt);
      break;
    }
    int pb = b + (1 << lvl);
    if (t == 0) {
      u64 f;
      do { f = atomicAdd(&flag2[pb], 0ull); __builtin_amdgcn_s_sleep(1); } while ((f >> 32) == 0ull);
      shInt[0] = (int)(u32)f;
    }
    __syncthreads();
    __threadfence();                       // acquire partner subtree
    int nR = shInt[0];
    int nL = myCnt;
    int slotL = b * REGSLOT, slotR = pb * REGSLOT;
    if (t == 0) {
      int a = 0, bb = 0, hasM = 0;
      if (nL > 0 && nR > 0) {
        int gstartR = (int)regS[pb];
        int gendR   = (int)regS[b + (2 << lvl)];
        int2 rL = REC[slotL + nL - 1];
        float SYL = recSY(rL); int stL = rL.x;
        int2 rR = REC[slotR];
        float SYR = recSY(rR);
        int eR = (nR > 1) ? (REC[slotR + 1].x - 1) : (gendR - 1);
        float SWL = wsumf(stL, gstartR - 1);
        float SWR = wsumf(gstartR, eR);
        if (SYL * SWR <= SYR * SWL) {
          hasM = 1;
          float SYM = SYL + SYR; int Ms = stL, Me = eR;
          a = 1; bb = 1;
          for (;;) {
            float SWM = wsumf(Ms, Me);
            if (a < nL) {
              int2 re = REC[slotL + nL - 1 - a];
              float SYe = recSY(re); int ste = re.x;
              float SWe = wsumf(ste, Ms - 1);
              if (SYe * SWM <= SYM * SWe) { SYM += SYe; Ms = ste; ++a; continue; }
            }
            if (bb < nR) {
              int2 rb = REC[slotR + bb];
              float SYb = recSY(rb); int sb = rb.x;
              int eb = (bb + 1 < nR) ? (REC[slotR + bb + 1].x - 1) : (gendR - 1);
              float SWb = wsumf(sb, eb);
              if (SYM * SWb <= SYb * SWM) { SYM += SYb; Me = eb; ++bb; continue; }
            }
            break;
          }
          REC[slotL + nL - a] = make_int2(Ms, __float_as_int(SYM));
        }
      }
      shInt[1] = a; shInt[2] = bb; shInt[3] = hasM;
    }
    __syncthreads();
    int a = shInt[1], bb = shInt[2], hasM = shInt[3];
    int destBase = slotL + nL - a + hasM;
    int srcBase = slotR + bb;
    int ncopy = nR - bb;
    for (int off = 0; off < ncopy; off += 256) {   // staged, dest<=src, in order
      int k2 = off + t; bool act = k2 < ncopy;
      int2 vr = make_int2(0, 0);
      if (act) vr = REC[srcBase + k2];
      __syncthreads();
      if (act) REC[destBase + k2] = vr;
      __syncthreads();
    }
    __syncthreads();
    myCnt = nL - a + hasM + (nR - bb);
    ++lvl;
  }
  // ---- out phase: wait for root, then 2048 items per block ----
  if (t == 0) {
    u64 f;
    do { f = atomicAdd(&flag2[0], 0ull); __builtin_amdgcn_s_sleep(2); } while ((f >> 32) != 2ull);
    shInt[0] = (int)(u32)f;
  }
  __syncthreads();
  __threadfence();                         // acquire final REC + all cdf writes
  int m = shInt[0];
  bool useL = (m <= CH_PER_BLK * PAD);
  if (useL) {                              // stage final record table into LDS
    for (int k = t; k < m; k += 256) {
      int2 r = REC[k];
      rST[k] = r.x; rSY[k] = __int_as_float(r.y);
    }
  }
  __syncthreads();
  u32 kmin = mm[0], kmax = mm[1];
  float smax = key_to_score(kmin);
  for (int q = 0; q < 8; ++q) {
    int i = b * 2048 + q * 256 + t;
    u32 key = keyRaw[i];
    u32 g = bucket_of(key, kmin, kmax);
    int p = (int)cdf[g];                   // bucket-aligned position of bucket start
    int lo = 0, hi = m - 1;
    if (useL) {
      while (lo < hi) {
        int mid = (lo + hi + 1) >> 1;
        if (rST[mid] <= p) lo = mid; else hi = mid - 1;
      }
      int s0 = rST[lo];
      int e0 = (lo + 1 < m) ? (rST[lo + 1] - 1) : (N_ITEMS - 1);
      float SW = wsumf(s0, e0);
      float sc = key_to_score(key);
      float rank = fexp(sc - smax) * SW / rSY[lo];
      out[i] = floorf(rank * (1.0f / 3.0f)) + 1.0f;
    } else {
      while (lo < hi) {
        int mid = (lo + hi + 1) >> 1;
        if (REC[mid].x <= p) lo = mid; else hi = mid - 1;
      }
      int2 r = REC[lo];
      int s0 = r.x;
      int e0 = (lo + 1 < m) ? (REC[lo + 1].x - 1) : (N_ITEMS - 1);
      float SW = wsumf(s0, e0);
      float sc = key_to_score(key);
      float rank = fexp(sc - smax) * SW / recSY(r);
      out[i] = floorf(rank * (1.0f / 3.0f)) + 1.0f;
    }
  }
}

// ---------- launch ----------

extern "C" void kernel_launch(void* const* d_in, const int* in_sizes, int n_in,
                              void* d_out, int out_size, void* d_ws, size_t ws_size,
                              hipStream_t stream) {
  const float* x  = (const float*)d_in[0];
  const float* w1 = (const float*)d_in[1];
  const float* b1 = (const float*)d_in[2];
  const float* w2 = (const float*)d_in[3];
  const float* b2 = (const float*)d_in[4];
  float* out = (float*)d_out;

  char* ws = (char*)d_ws;
  size_t o = 0;
  u32* mm     = (u32*)(ws + o); o += 16;
  u32* pmin   = (u32*)(ws + o); o += (size_t)512 * 4;
  u32* pmax   = (u32*)(ws + o); o += (size_t)512 * 4;
  u32* cdf    = (u32*)(ws + o); o += (size_t)(NB + 4) * 4;
  u32* keyRaw = (u32*)(ws + o); o += (size_t)N_ITEMS * 4;
  int2* REC   = (int2*)(ws + o); o += (size_t)N_ITEMS * 8;
  // ---- zero-initialized control region (one contiguous memset) ----
  char* zbase = ws + o;
  u64* hist8  = (u64*)(ws + o); o += (size_t)NSLICE * NB * 8;    // 4 MB, XCD-sliced
  u64* flags  = (u64*)(ws + o); o += (size_t)MBLK * 8;
  u64* flag2  = (u64*)(ws + o); o += (size_t)MBLK * 8;
  u32* done   = (u32*)(ws + o); o += 64;
  size_t zbytes = (size_t)((ws + o) - zbase);

  hipMemsetAsync(zbase, 0, zbytes, stream);
  score_hist_kernel<<<512, 256, 0, stream>>>(x, w1, b1, w2, b2,
                                             keyRaw, pmin, pmax, done, hist8, mm);
  solve_kernel<<<MBLK, 256, 0, stream>>>(hist8, flags, flag2, cdf, REC, keyRaw, mm, out);
}

// Round 2
// 142.883 us; speedup vs baseline: 1.2903x; 1.2903x over previous
//
#include <hip/hip_runtime.h>
#include <stdint.h>

typedef unsigned int u32;
typedef unsigned long long u64;

#define N_ITEMS 131072
#define NB 131072                   // buckets (monotone in descending score)
#define NSLICE 4                    // XCD-sliced histogram copies
#define MBLK 64                     // fused scan/pav/merge blocks
#define BUCK_PER_BLK 2048           // buckets per fused block
#define CH_PER_BLK 32               // chunks (64 buckets) per fused block
#define PAD 65                      // padded LDS record stride per chunk
#define REGSLOT 2048                // record slots per region in global REC
#define FIXSCALE 268435456.0f       // 2^28 fixed-point scale for sum(exp)
#define FIXMASK ((1ull << 46) - 1)

// ---------- helpers ----------

// sum_{i=s}^{e} (N - i) — exact weight-side sum of exp(w) over sorted positions
__device__ __forceinline__ float wsumf(int s, int e) {
  return 0.5f * (float)(e - s + 1) * (float)(2 * N_ITEMS - s - e);
}

__device__ __forceinline__ float key_to_score(u32 key) {
  u32 m = ~key;
  u32 u = (m & 0x80000000u) ? (m ^ 0x80000000u) : ~m;
  return __uint_as_float(u);
}

#define LOG2E 1.4426950408889634f
__device__ __forceinline__ float fexp(float x) { return exp2f(x * LOG2E); }

// ascending key == descending score; ascending bucket == descending score
__device__ __forceinline__ u32 bucket_of(u32 key, u32 kmin, u32 kmax) {
  double scale = (double)NB / ((double)(kmax - kmin) + 1.0);
  u32 b = (u32)((double)(key - kmin) * scale);
  return b < NB ? b : (NB - 1);
}

__device__ __forceinline__ float recSY(int2 r) { return __int_as_float(r.y); }

// ---------- 1) scores -> keys; block minmax folded straight into 2 global atomics ----------
// agg[0] accumulates max(~key) == ~min(key); agg[1] accumulates max(key). Both init 0.

__global__ __launch_bounds__(256) void score_key_kernel(
    const float* __restrict__ x,
    const float* __restrict__ w1, const float* __restrict__ b1,
    const float* __restrict__ w2, const float* __restrict__ b2,
    u32* __restrict__ keyRaw, u32* __restrict__ agg) {
  __shared__ u32 wmn[4], wmx[4];
  int t = threadIdx.x;
  int i = blockIdx.x * 256 + t;
  float xv = x[i];
  float s = b2[0];
#pragma unroll
  for (int j = 0; j < 32; ++j) {
    float h = fmaf(xv, w1[j], b1[j]);
    h = fmaxf(h, 0.0f);
    s = fmaf(h, w2[j], s);
  }
  u32 u = __float_as_uint(s);
  u32 m = u ^ ((u & 0x80000000u) ? 0xFFFFFFFFu : 0x80000000u); // ascending map
  u32 key = ~m;
  keyRaw[i] = key;
  u32 mn = key, mx = key;
#pragma unroll
  for (int off = 32; off > 0; off >>= 1) {
    mn = min(mn, (u32)__shfl_xor((int)mn, off));
    mx = max(mx, (u32)__shfl_xor((int)mx, off));
  }
  if ((t & 63) == 0) { wmn[t >> 6] = mn; wmx[t >> 6] = mx; }
  __syncthreads();
  if (t == 0) {
    mn = min(min(wmn[0], wmn[1]), min(wmn[2], wmn[3]));
    mx = max(max(wmx[0], wmx[1]), max(wmx[2], wmx[3]));
    atomicMax(&agg[0], ~mn);
    atomicMax(&agg[1], mx);
  }
}

// ---------- 2) bucket aggregates: ONE packed u64 atomic per item, XCD-sliced ----------
// bits [46:63] = count, bits [0:45] = fixed-point (2^28) sum of exp(s - smax)

__global__ __launch_bounds__(256) void hist_kernel(
    const u32* __restrict__ keyRaw, const u32* __restrict__ agg,
    u64* __restrict__ hist8) {
  int t = threadIdx.x;
  int i = blockIdx.x * 256 + t;
  u32 kmin = ~agg[0], kmax = agg[1];
  u32 key = keyRaw[i];
  u32 g = bucket_of(key, kmin, kmax);
  float smax = key_to_score(kmin);
  float v = fexp(key_to_score(key) - smax);            // in (0, 1]
  u64 fix = (u64)fmaxf(1.0f, fmaf(v, FIXSCALE, 0.5f)); // clamp: SY can never be 0
  size_t slice = (size_t)(blockIdx.x & (NSLICE - 1)) * NB;
  atomicAdd(&hist8[slice + g], (1ull << 46) | fix);
}

// ---------- 3) fused: scan + PAV + in-LDS merges + cross-block region tree + out ----------
// 64 blocks x 256. Tree levels 0..5 at region granularity via flag2 release/acquire.
// After block 0 publishes the root, all blocks run the out phase (2048 items each).

__global__ __launch_bounds__(256) void solve_kernel(
    const u64* __restrict__ hist8, u64* __restrict__ flags, u64* __restrict__ flag2,
    u32* __restrict__ cdf, int2* __restrict__ REC,
    const u32* __restrict__ keyRaw, const u32* __restrict__ agg,
    float* __restrict__ out) {
  __shared__ u32 vals[BUCK_PER_BLK + 1];   // counts -> global-exclusive cdf
  __shared__ float seL[BUCK_PER_BLK];
  __shared__ int   rST[CH_PER_BLK * PAD];
  __shared__ float rSY[CH_PER_BLK * PAD];
  __shared__ u32 sh[256];
  __shared__ u32 aggS[64];
  __shared__ u32 regS[65];                 // region start positions (global item idx)
  __shared__ int lcnt[CH_PER_BLK];
  __shared__ int ca[16], cb[16], cM[16];
  __shared__ int shInt[4];
  int t = threadIdx.x, b = blockIdx.x;
  int B0 = b * BUCK_PER_BLK;
  // coalesced load + slice reduce
  for (int q = 0; q < 8; ++q) {
    int ii = q * 256 + t;
    u64 acc = 0;
#pragma unroll
    for (int c = 0; c < NSLICE; ++c) acc += hist8[(size_t)c * NB + B0 + ii];
    vals[ii] = (u32)(acc >> 46);
    seL[ii] = (float)(acc & FIXMASK) * (1.0f / FIXSCALE);
  }
  __syncthreads();
  // per-thread local prefix over contiguous 8, then block scan
  u32 loc[8]; u32 s = 0;
  for (int q = 0; q < 8; ++q) { loc[q] = s; s += vals[t * 8 + q]; }
  sh[t] = s;
  __syncthreads();
  for (int off = 1; off < 256; off <<= 1) {
    u32 x2 = (t >= off) ? sh[t - off] : 0u;
    __syncthreads();
    sh[t] += x2;
    __syncthreads();
  }
  // publish aggregate; wait-all over ALL 64 blocks (full prefix needed for the tree)
  if (t == 0) atomicExch(&flags[b], (1ull << 32) | (u64)sh[255]);
  if (t < 64) {
    u64 f;
    do { f = atomicAdd(&flags[t], 0ull); } while ((u32)(f >> 32) == 0u);
    aggS[t] = (u32)f;
  }
  __syncthreads();
  if (t < 64) {                 // wave-level exclusive scan over 64 aggregates
    u32 v = aggS[t];
    u32 inc = v;
    for (int off = 1; off < 64; off <<= 1) {
      u32 o2 = __shfl_up(inc, off);
      if (t >= off) inc += o2;
    }
    regS[t] = inc - v;
    if (t == 63) regS[64] = inc;          // == N_ITEMS
  }
  __syncthreads();
  u32 exclu = regS[b];
  u32 tbase = ((t == 0) ? 0u : sh[t - 1]) + exclu;
  // overwrite vals with GLOBAL exclusive cdf; mirror to global (vectorized)
  u32 eb8[8];
  for (int q = 0; q < 8; ++q) { eb8[q] = tbase + loc[q]; vals[t * 8 + q] = eb8[q]; }
  {
    uint4* c4 = (uint4*)(cdf + B0 + t * 8);
    c4[0] = make_uint4(eb8[0], eb8[1], eb8[2], eb8[3]);
    c4[1] = make_uint4(eb8[4], eb8[5], eb8[6], eb8[7]);
  }
  if (t == 255) vals[BUCK_PER_BLK] = exclu + sh[255];
  __syncthreads();
  // per-chunk PAV (32 threads), stack stored in place at padded stride
  if (t < CH_PER_BLK) {
    int base = t * PAD;
    int ptr = 0; bool have = false;
    float syT = 0.0f; int stT = 0;
    for (int k = 0; k < 64; ++k) {
      u32 cs = vals[t * 64 + k], ce = vals[t * 64 + k + 1];
      if (ce == cs) continue;                 // empty bucket
      float syC = seL[t * 64 + k];
      int stC = (int)cs, eC = (int)ce - 1;
      while (have) {
        float SWc = wsumf(stC, eC);
        float SWt = wsumf(stT, stC - 1);
        if (!(syT * SWc <= syC * SWt)) break; // merge while val_top <= val_cur
        syC += syT; stC = stT;
        if (ptr == 0) { have = false; break; }
        --ptr;
        stT = rST[base + ptr]; syT = rSY[base + ptr];
      }
      if (have) { rST[base + ptr] = stT; rSY[base + ptr] = syT; ++ptr; }
      stT = stC; syT = syC; have = true;
    }
    if (have) { rST[base + ptr] = stT; rSY[base + ptr] = syT; ++ptr; }
    lcnt[t] = ptr;
  }
  __syncthreads();
  // merge levels 0..4 entirely in LDS; copies wave-parallel across disjoint pairs
  for (int j = 0; j < 5; ++j) {
    int P = CH_PER_BLK >> (j + 1);
    if (t < P) {
      int p = t;
      int kL = p << (j + 1), kR = kL + (1 << j);
      int slotL = kL * PAD, slotR = kR * PAD;
      int nL = lcnt[kL], nR = lcnt[kR];
      int a = 0, bb = 0, hasM = 0;
      if (nL > 0 && nR > 0) {
        int gstartR = (int)vals[kR * 64];
        int gendR   = (int)vals[(kR + (1 << j)) * 64];
        float SYL = rSY[slotL + nL - 1]; int stL = rST[slotL + nL - 1];
        float SYR = rSY[slotR];
        int eR = (nR > 1) ? (rST[slotR + 1] - 1) : (gendR - 1);
        float SWL = wsumf(stL, gstartR - 1);
        float SWR = wsumf(gstartR, eR);
        if (SYL * SWR <= SYR * SWL) {
          hasM = 1;
          float SYM = SYL + SYR; int Ms = stL, Me = eR;
          a = 1; bb = 1;
          for (;;) {
            float SWM = wsumf(Ms, Me);
            if (a < nL) {
              float SYe = rSY[slotL + nL - 1 - a]; int ste = rST[slotL + nL - 1 - a];
              float SWe = wsumf(ste, Ms - 1);
              if (SYe * SWM <= SYM * SWe) { SYM += SYe; Ms = ste; ++a; continue; }
            }
            if (bb < nR) {
              float SYb = rSY[slotR + bb]; int sb = rST[slotR + bb];
              int eb = (bb + 1 < nR) ? (rST[slotR + bb + 1] - 1) : (gendR - 1);
              float SWb = wsumf(sb, eb);
              if (SYM * SWb <= SYb * SWM) { SYM += SYb; Me = eb; ++bb; continue; }
            }
            break;
          }
          rST[slotL + nL - a] = Ms; rSY[slotL + nL - a] = SYM;
        }
      }
      ca[p] = a; cb[p] = bb; cM[p] = hasM;
    }
    __syncthreads();
    {
      int w = t >> 6, lane = t & 63;
      for (int p = w; p < P; p += 4) {      // pairs are disjoint -> waves in parallel
        int kL = p << (j + 1), kR = kL + (1 << j);
        int nL = lcnt[kL], nR = lcnt[kR];
        int a = ca[p], bb = cb[p], hasM = cM[p];
        int destBase = kL * PAD + nL - a + hasM;
        int srcBase = kR * PAD + bb;
        int ncopy = nR - bb;
        for (int off = 0; off < ncopy; off += 64) {  // wave-staged, dest<=src, in order
          int k2 = off + lane; bool act = k2 < ncopy;
          int vt = 0; float vs = 0.f;
          if (act) { vt = rST[srcBase + k2]; vs = rSY[srcBase + k2]; }
          if (act) { rST[destBase + k2] = vt; rSY[destBase + k2] = vs; }
        }
      }
    }
    __syncthreads();
    if (t < P) {
      int p = t; int kL = p << (j + 1), kR = kL + (1 << j);
      lcnt[kL] = lcnt[kL] - ca[p] + cM[p] + (lcnt[kR] - cb[p]);
    }
    __syncthreads();
  }
  // write region records (coalesced)
  int myCnt = lcnt[0];
  for (int k = t; k < myCnt; k += 256)
    REC[(size_t)b * REGSLOT + k] = make_int2(rST[k], __float_as_int(rSY[k]));
  __syncthreads();
  // ---- cross-block region tree, levels 0..5 ----
  int lvl = 0;
  for (;;) {
    if (b & (1 << lvl)) {                  // right child: publish subtree, leave tree
      __threadfence();
      if (t == 0) atomicExch(&flag2[b], (1ull << 32) | (u64)(u32)myCnt);
      break;
    }
    if (lvl == 6) {                        // b == 0: root done
      __threadfence();
      if (t == 0) atomicExch(&flag2[0], (2ull << 32) | (u64)(u32)myCnt);
      break;
    }
    int pb = b + (1 << lvl);
    if (t == 0) {
      u64 f;
      do { f = atomicAdd(&flag2[pb], 0ull); __builtin_amdgcn_s_sleep(1); } while ((f >> 32) == 0ull);
      shInt[0] = (int)(u32)f;
    }
    __syncthreads();
    __threadfence();                       // acquire partner subtree
    int nR = shInt[0];
    int nL = myCnt;
    int slotL = b * REGSLOT, slotR = pb * REGSLOT;
    if (t == 0) {
      int a = 0, bb = 0, hasM = 0;
      if (nL > 0 && nR > 0) {
        int gstartR = (int)regS[pb];
        int gendR   = (int)regS[b + (2 << lvl)];
        int2 rL = REC[slotL + nL - 1];
        float SYL = recSY(rL); int stL = rL.x;
        int2 rR = REC[slotR];
        float SYR = recSY(rR);
        int eR = (nR > 1) ? (REC[slotR + 1].x - 1) : (gendR - 1);
        float SWL = wsumf(stL, gstartR - 1);
        float SWR = wsumf(gstartR, eR);
        if (SYL * SWR <= SYR * SWL) {
          hasM = 1;
          float SYM = SYL + SYR; int Ms = stL, Me = eR;
          a = 1; bb = 1;
          for (;;) {
            float SWM = wsumf(Ms, Me);
            if (a < nL) {
              int2 re = REC[slotL + nL - 1 - a];
              float SYe = recSY(re); int ste = re.x;
              float SWe = wsumf(ste, Ms - 1);
              if (SYe * SWM <= SYM * SWe) { SYM += SYe; Ms = ste; ++a; continue; }
            }
            if (bb < nR) {
              int2 rb = REC[slotR + bb];
              float SYb = recSY(rb); int sb = rb.x;
              int eb = (bb + 1 < nR) ? (REC[slotR + bb + 1].x - 1) : (gendR - 1);
              float SWb = wsumf(sb, eb);
              if (SYM * SWb <= SYb * SWM) { SYM += SYb; Me = eb; ++bb; continue; }
            }
            break;
          }
          REC[slotL + nL - a] = make_int2(Ms, __float_as_int(SYM));
        }
      }
      shInt[1] = a; shInt[2] = bb; shInt[3] = hasM;
    }
    __syncthreads();
    int a = shInt[1], bb = shInt[2], hasM = shInt[3];
    int destBase = slotL + nL - a + hasM;
    int srcBase = slotR + bb;
    int ncopy = nR - bb;
    for (int off = 0; off < ncopy; off += 256) {   // staged, dest<=src, in order
      int k2 = off + t; bool act = k2 < ncopy;
      int2 vr = make_int2(0, 0);
      if (act) vr = REC[srcBase + k2];
      __syncthreads();
      if (act) REC[destBase + k2] = vr;
      __syncthreads();
    }
    __syncthreads();
    myCnt = nL - a + hasM + (nR - bb);
    ++lvl;
  }
  // ---- out phase: wait for root, then 2048 items per block ----
  if (t == 0) {
    u64 f;
    do { f = atomicAdd(&flag2[0], 0ull); __builtin_amdgcn_s_sleep(2); } while ((f >> 32) != 2ull);
    shInt[0] = (int)(u32)f;
  }
  __syncthreads();
  __threadfence();                         // acquire final REC + all cdf writes
  int m = shInt[0];
  bool useL = (m <= CH_PER_BLK * PAD);
  if (useL) {                              // stage final record table into LDS
    for (int k = t; k < m; k += 256) {
      int2 r = REC[k];
      rST[k] = r.x; rSY[k] = __int_as_float(r.y);
    }
  }
  __syncthreads();
  u32 kmin = ~agg[0], kmax = agg[1];
  float smax = key_to_score(kmin);
  for (int q = 0; q < 8; ++q) {
    int i = b * 2048 + q * 256 + t;
    u32 key = keyRaw[i];
    u32 g = bucket_of(key, kmin, kmax);
    int p = (int)cdf[g];                   // bucket-aligned position of bucket start
    int lo = 0, hi = m - 1;
    if (useL) {
      while (lo < hi) {
        int mid = (lo + hi + 1) >> 1;
        if (rST[mid] <= p) lo = mid; else hi = mid - 1;
      }
      int s0 = rST[lo];
      int e0 = (lo + 1 < m) ? (rST[lo + 1] - 1) : (N_ITEMS - 1);
      float SW = wsumf(s0, e0);
      float sc = key_to_score(key);
      float rank = fexp(sc - smax) * SW / rSY[lo];
      out[i] = floorf(rank * (1.0f / 3.0f)) + 1.0f;
    } else {
      while (lo < hi) {
        int mid = (lo + hi + 1) >> 1;
        if (REC[mid].x <= p) lo = mid; else hi = mid - 1;
      }
      int2 r = REC[lo];
      int s0 = r.x;
      int e0 = (lo + 1 < m) ? (REC[lo + 1].x - 1) : (N_ITEMS - 1);
      float SW = wsumf(s0, e0);
      float sc = key_to_score(key);
      float rank = fexp(sc - smax) * SW / recSY(r);
      out[i] = floorf(rank * (1.0f / 3.0f)) + 1.0f;
    }
  }
}

// ---------- launch ----------

extern "C" void kernel_launch(void* const* d_in, const int* in_sizes, int n_in,
                              void* d_out, int out_size, void* d_ws, size_t ws_size,
                              hipStream_t stream) {
  const float* x  = (const float*)d_in[0];
  const float* w1 = (const float*)d_in[1];
  const float* b1 = (const float*)d_in[2];
  const float* w2 = (const float*)d_in[3];
  const float* b2 = (const float*)d_in[4];
  float* out = (float*)d_out;

  char* ws = (char*)d_ws;
  size_t o = 0;
  u32* cdf    = (u32*)(ws + o); o += (size_t)(NB + 4) * 4;
  u32* keyRaw = (u32*)(ws + o); o += (size_t)N_ITEMS * 4;
  int2* REC   = (int2*)(ws + o); o += (size_t)N_ITEMS * 8;
  // ---- zero-initialized control region (one contiguous memset) ----
  char* zbase = ws + o;
  u64* hist8  = (u64*)(ws + o); o += (size_t)NSLICE * NB * 8;    // 4 MB, XCD-sliced
  u64* flags  = (u64*)(ws + o); o += (size_t)MBLK * 8;
  u64* flag2  = (u64*)(ws + o); o += (size_t)MBLK * 8;
  u32* agg    = (u32*)(ws + o); o += 64;
  size_t zbytes = (size_t)((ws + o) - zbase);

  hipMemsetAsync(zbase, 0, zbytes, stream);
  score_key_kernel<<<512, 256, 0, stream>>>(x, w1, b1, w2, b2, keyRaw, agg);
  hist_kernel<<<512, 256, 0, stream>>>(keyRaw, agg, hist8);
  solve_kernel<<<MBLK, 256, 0, stream>>>(hist8, flags, flag2, cdf, REC, keyRaw, agg, out);
}

// Round 3
// 139.381 us; speedup vs baseline: 1.3227x; 1.0251x over previous
//
#include <hip/hip_runtime.h>
#include <stdint.h>

typedef unsigned int u32;
typedef unsigned long long u64;

#define N_ITEMS 131072
#define NB 131072                   // buckets (monotone in descending score)
#define NSLICE 4                    // XCD-sliced histogram copies
#define MBLK 64                     // fused scan/pav/merge blocks
#define BUCK_PER_BLK 2048           // buckets per fused block
#define CH_PER_BLK 32               // chunks (64 buckets) per fused block
#define PAD 65                      // padded LDS record stride per chunk
#define REGSLOT 2048                // record slots per region in global REC
#define FPAD 16                     // u64s per flag slot -> 128B (own cacheline)
#define FIXSCALE 268435456.0f       // 2^28 fixed-point scale for sum(exp)
#define FIXMASK ((1ull << 46) - 1)

// ---------- helpers ----------

// sum_{i=s}^{e} (N - i) — exact weight-side sum of exp(w) over sorted positions
__device__ __forceinline__ float wsumf(int s, int e) {
  return 0.5f * (float)(e - s + 1) * (float)(2 * N_ITEMS - s - e);
}

__device__ __forceinline__ float key_to_score(u32 key) {
  u32 m = ~key;
  u32 u = (m & 0x80000000u) ? (m ^ 0x80000000u) : ~m;
  return __uint_as_float(u);
}

#define LOG2E 1.4426950408889634f
__device__ __forceinline__ float fexp(float x) { return exp2f(x * LOG2E); }

// ascending key == descending score; ascending bucket == descending score
__device__ __forceinline__ u32 bucket_of(u32 key, u32 kmin, u32 kmax) {
  double scale = (double)NB / ((double)(kmax - kmin) + 1.0);
  u32 b = (u32)((double)(key - kmin) * scale);
  return b < NB ? b : (NB - 1);
}

__device__ __forceinline__ float recSY(int2 r) { return __int_as_float(r.y); }

// relaxed agent-scope load: polls WITHOUT taking exclusive line ownership
__device__ __forceinline__ u64 agent_ld(const u64* p) {
  return __hip_atomic_load(p, __ATOMIC_RELAXED, __HIP_MEMORY_SCOPE_AGENT);
}

// ---------- 1) scores -> keys; block minmax -> 2 global atomics; zero hist8 ----------
// agg[0] accumulates max(~key) == ~min(key); agg[1] accumulates max(key). Both init 0.

__global__ __launch_bounds__(256) void score_key_kernel(
    const float* __restrict__ x,
    const float* __restrict__ w1, const float* __restrict__ b1,
    const float* __restrict__ w2, const float* __restrict__ b2,
    u32* __restrict__ keyRaw, u32* __restrict__ agg, u64* __restrict__ hist8) {
  __shared__ u32 wmn[4], wmx[4];
  int t = threadIdx.x;
  int i = blockIdx.x * 256 + t;
  // zero the 4 MB sliced histogram (2 x uint4 per thread, coalesced)
  {
    uint4 z = make_uint4(0u, 0u, 0u, 0u);
    ((uint4*)hist8)[i] = z;
    ((uint4*)hist8)[i + N_ITEMS] = z;
  }
  float xv = x[i];
  float s = b2[0];
#pragma unroll
  for (int j = 0; j < 32; ++j) {
    float h = fmaf(xv, w1[j], b1[j]);
    h = fmaxf(h, 0.0f);
    s = fmaf(h, w2[j], s);
  }
  u32 u = __float_as_uint(s);
  u32 m = u ^ ((u & 0x80000000u) ? 0xFFFFFFFFu : 0x80000000u); // ascending map
  u32 key = ~m;
  keyRaw[i] = key;
  u32 mn = key, mx = key;
#pragma unroll
  for (int off = 32; off > 0; off >>= 1) {
    mn = min(mn, (u32)__shfl_xor((int)mn, off));
    mx = max(mx, (u32)__shfl_xor((int)mx, off));
  }
  if ((t & 63) == 0) { wmn[t >> 6] = mn; wmx[t >> 6] = mx; }
  __syncthreads();
  if (t == 0) {
    mn = min(min(wmn[0], wmn[1]), min(wmn[2], wmn[3]));
    mx = max(max(wmx[0], wmx[1]), max(wmx[2], wmx[3]));
    atomicMax(&agg[0], ~mn);
    atomicMax(&agg[1], mx);
  }
}

// ---------- 2) bucket aggregates: ONE packed u64 atomic per item, XCD-sliced ----------
// bits [46:63] = count, bits [0:45] = fixed-point (2^28) sum of exp(s - smax)

__global__ __launch_bounds__(256) void hist_kernel(
    const u32* __restrict__ keyRaw, const u32* __restrict__ agg,
    u64* __restrict__ hist8) {
  int t = threadIdx.x;
  int i = blockIdx.x * 256 + t;
  u32 kmin = ~agg[0], kmax = agg[1];
  u32 key = keyRaw[i];
  u32 g = bucket_of(key, kmin, kmax);
  float smax = key_to_score(kmin);
  float v = fexp(key_to_score(key) - smax);            // in (0, 1]
  u64 fix = (u64)fmaxf(1.0f, fmaf(v, FIXSCALE, 0.5f)); // clamp: SY can never be 0
  size_t slice = (size_t)(blockIdx.x & (NSLICE - 1)) * NB;
  atomicAdd(&hist8[slice + g], (1ull << 46) | fix);
}

// ---------- 3) fused: scan + PAV + in-LDS merges + cross-block region tree + out ----------
// 64 blocks x 256. Tree levels 0..5 at region granularity; flags padded to 128B slots;
// all polling is load-only (no RMW ping-pong). After block 0 publishes the root,
// all blocks run the out phase (2048 items each).

__global__ __launch_bounds__(256) void solve_kernel(
    const u64* __restrict__ hist8, u64* __restrict__ flags, u64* __restrict__ flag2,
    u32* __restrict__ cdf, int2* __restrict__ REC,
    const u32* __restrict__ keyRaw, const u32* __restrict__ agg,
    float* __restrict__ out) {
  __shared__ u32 vals[BUCK_PER_BLK + 1];   // counts -> global-exclusive cdf
  __shared__ float seL[BUCK_PER_BLK];
  __shared__ int   rST[CH_PER_BLK * PAD];  // PAV stacks; later: walk caches; later: out table
  __shared__ float rSY[CH_PER_BLK * PAD];
  __shared__ u32 sh[256];
  __shared__ u32 aggS[64];
  __shared__ u32 regS[65];                 // region start positions (global item idx)
  __shared__ int lcnt[CH_PER_BLK];
  __shared__ int ca[16], cb[16], cM[16];
  __shared__ int shInt[4];
  int t = threadIdx.x, b = blockIdx.x;
  int B0 = b * BUCK_PER_BLK;
  // coalesced load + slice reduce
  for (int q = 0; q < 8; ++q) {
    int ii = q * 256 + t;
    u64 acc = 0;
#pragma unroll
    for (int c = 0; c < NSLICE; ++c) acc += hist8[(size_t)c * NB + B0 + ii];
    vals[ii] = (u32)(acc >> 46);
    seL[ii] = (float)(acc & FIXMASK) * (1.0f / FIXSCALE);
  }
  __syncthreads();
  // per-thread local prefix over contiguous 8, then block scan
  u32 loc[8]; u32 s = 0;
  for (int q = 0; q < 8; ++q) { loc[q] = s; s += vals[t * 8 + q]; }
  sh[t] = s;
  __syncthreads();
  for (int off = 1; off < 256; off <<= 1) {
    u32 x2 = (t >= off) ? sh[t - off] : 0u;
    __syncthreads();
    sh[t] += x2;
    __syncthreads();
  }
  // publish aggregate; wait-all over ALL 64 blocks (load-only polling, padded slots)
  if (t == 0) atomicExch(&flags[(size_t)b * FPAD], (1ull << 32) | (u64)sh[255]);
  if (t < 64) {
    u64 f;
    do { f = agent_ld(&flags[(size_t)t * FPAD]); } while ((u32)(f >> 32) == 0u);
    aggS[t] = (u32)f;
  }
  __syncthreads();
  if (t < 64) {                 // wave-level exclusive scan over 64 aggregates
    u32 v = aggS[t];
    u32 inc = v;
    for (int off = 1; off < 64; off <<= 1) {
      u32 o2 = __shfl_up(inc, off);
      if (t >= off) inc += o2;
    }
    regS[t] = inc - v;
    if (t == 63) regS[64] = inc;          // == N_ITEMS
  }
  __syncthreads();
  u32 exclu = regS[b];
  u32 tbase = ((t == 0) ? 0u : sh[t - 1]) + exclu;
  // overwrite vals with GLOBAL exclusive cdf; mirror to global (vectorized)
  u32 eb8[8];
  for (int q = 0; q < 8; ++q) { eb8[q] = tbase + loc[q]; vals[t * 8 + q] = eb8[q]; }
  {
    uint4* c4 = (uint4*)(cdf + B0 + t * 8);
    c4[0] = make_uint4(eb8[0], eb8[1], eb8[2], eb8[3]);
    c4[1] = make_uint4(eb8[4], eb8[5], eb8[6], eb8[7]);
  }
  if (t == 255) vals[BUCK_PER_BLK] = exclu + sh[255];
  __syncthreads();
  // per-chunk PAV (32 threads), stack stored in place at padded stride
  if (t < CH_PER_BLK) {
    int base = t * PAD;
    int ptr = 0; bool have = false;
    float syT = 0.0f; int stT = 0;
    for (int k = 0; k < 64; ++k) {
      u32 cs = vals[t * 64 + k], ce = vals[t * 64 + k + 1];
      if (ce == cs) continue;                 // empty bucket
      float syC = seL[t * 64 + k];
      int stC = (int)cs, eC = (int)ce - 1;
      while (have) {
        float SWc = wsumf(stC, eC);
        float SWt = wsumf(stT, stC - 1);
        if (!(syT * SWc <= syC * SWt)) break; // merge while val_top <= val_cur
        syC += syT; stC = stT;
        if (ptr == 0) { have = false; break; }
        --ptr;
        stT = rST[base + ptr]; syT = rSY[base + ptr];
      }
      if (have) { rST[base + ptr] = stT; rSY[base + ptr] = syT; ++ptr; }
      stT = stC; syT = syC; have = true;
    }
    if (have) { rST[base + ptr] = stT; rSY[base + ptr] = syT; ++ptr; }
    lcnt[t] = ptr;
  }
  __syncthreads();
  // merge levels 0..4 entirely in LDS; copies wave-parallel across disjoint pairs
  for (int j = 0; j < 5; ++j) {
    int P = CH_PER_BLK >> (j + 1);
    if (t < P) {
      int p = t;
      int kL = p << (j + 1), kR = kL + (1 << j);
      int slotL = kL * PAD, slotR = kR * PAD;
      int nL = lcnt[kL], nR = lcnt[kR];
      int a = 0, bb = 0, hasM = 0;
      if (nL > 0 && nR > 0) {
        int gstartR = (int)vals[kR * 64];
        int gendR   = (int)vals[(kR + (1 << j)) * 64];
        float SYL = rSY[slotL + nL - 1]; int stL = rST[slotL + nL - 1];
        float SYR = rSY[slotR];
        int eR = (nR > 1) ? (rST[slotR + 1] - 1) : (gendR - 1);
        float SWL = wsumf(stL, gstartR - 1);
        float SWR = wsumf(gstartR, eR);
        if (SYL * SWR <= SYR * SWL) {
          hasM = 1;
          float SYM = SYL + SYR; int Ms = stL, Me = eR;
          a = 1; bb = 1;
          for (;;) {
            float SWM = wsumf(Ms, Me);
            if (a < nL) {
              float SYe = rSY[slotL + nL - 1 - a]; int ste = rST[slotL + nL - 1 - a];
              float SWe = wsumf(ste, Ms - 1);
              if (SYe * SWM <= SYM * SWe) { SYM += SYe; Ms = ste; ++a; continue; }
            }
            if (bb < nR) {
              float SYb = rSY[slotR + bb]; int sb = rST[slotR + bb];
              int eb = (bb + 1 < nR) ? (rST[slotR + bb + 1] - 1) : (gendR - 1);
              float SWb = wsumf(sb, eb);
              if (SYM * SWb <= SYb * SWM) { SYM += SYb; Me = eb; ++bb; continue; }
            }
            break;
          }
          rST[slotL + nL - a] = Ms; rSY[slotL + nL - a] = SYM;
        }
      }
      ca[p] = a; cb[p] = bb; cM[p] = hasM;
    }
    __syncthreads();
    {
      int w = t >> 6, lane = t & 63;
      for (int p = w; p < P; p += 4) {      // pairs are disjoint -> waves in parallel
        int kL = p << (j + 1), kR = kL + (1 << j);
        int nL = lcnt[kL], nR = lcnt[kR];
        int a = ca[p], bb = cb[p], hasM = cM[p];
        int destBase = kL * PAD + nL - a + hasM;
        int srcBase = kR * PAD + bb;
        int ncopy = nR - bb;
        for (int off = 0; off < ncopy; off += 64) {  // wave-staged, dest<=src, in order
          int k2 = off + lane; bool act = k2 < ncopy;
          int vt = 0; float vs = 0.f;
          if (act) { vt = rST[srcBase + k2]; vs = rSY[srcBase + k2]; }
          if (act) { rST[destBase + k2] = vt; rSY[destBase + k2] = vs; }
        }
      }
    }
    __syncthreads();
    if (t < P) {
      int p = t; int kL = p << (j + 1), kR = kL + (1 << j);
      lcnt[kL] = lcnt[kL] - ca[p] + cM[p] + (lcnt[kR] - cb[p]);
    }
    __syncthreads();
  }
  // write region records (coalesced)
  int myCnt = lcnt[0];
  for (int k = t; k < myCnt; k += 256)
    REC[(size_t)b * REGSLOT + k] = make_int2(rST[k], __float_as_int(rSY[k]));
  __syncthreads();
  // ---- cross-block region tree, levels 0..5 ----
  // cache accessors: rST/rSY[0..127] = L tail (depth order), [128..255] = R head
#define LRECC(idx_, st_, sy_) { int _a = (idx_); \
    if (_a < 128) { st_ = rST[_a]; sy_ = rSY[_a]; } \
    else { int2 _r = REC[slotL + nL - 1 - _a]; st_ = _r.x; sy_ = __int_as_float(_r.y); } }
#define RRECC(idx_, st_, sy_) { int _i = (idx_); \
    if (_i < 128) { st_ = rST[128 + _i]; sy_ = rSY[128 + _i]; } \
    else { int2 _r = REC[slotR + _i]; st_ = _r.x; sy_ = __int_as_float(_r.y); } }
#define RSTC(idx_, st_) { int _i = (idx_); \
    if (_i < 128) { st_ = rST[128 + _i]; } else { st_ = REC[slotR + _i].x; } }
  int lvl = 0;
  for (;;) {
    if (b & (1 << lvl)) {                  // right child: publish subtree, leave tree
      __threadfence();
      if (t == 0) atomicExch(&flag2[(size_t)b * FPAD], (1ull << 32) | (u64)(u32)myCnt);
      break;
    }
    if (lvl == 6) {                        // b == 0: root done
      __threadfence();
      if (t == 0) atomicExch(&flag2[0], (2ull << 32) | (u64)(u32)myCnt);
      break;
    }
    int pb = b + (1 << lvl);
    int nL = myCnt;
    int slotL = b * REGSLOT, slotR = pb * REGSLOT;
    // L-tail prefetch (own data) overlaps the partner poll below (waves 1-2)
    if (t >= 64 && t < 192) {
      int p2 = t - 64;
      if (p2 < nL) { int2 r = REC[slotL + nL - 1 - p2]; rST[p2] = r.x; rSY[p2] = __int_as_float(r.y); }
    }
    if (t == 0) {
      u64 f;
      do { f = agent_ld(&flag2[(size_t)pb * FPAD]); __builtin_amdgcn_s_sleep(1); } while ((f >> 32) == 0ull);
      shInt[0] = (int)(u32)f;
    }
    __syncthreads();
    __threadfence();                       // acquire partner subtree
    int nR = shInt[0];
    // R-head prefetch (partner data, now valid)
    if (t >= 64 && t < 192) {
      int p2 = t - 64;
      if (p2 < nR) { int2 r = REC[slotR + p2]; rST[128 + p2] = r.x; rSY[128 + p2] = __int_as_float(r.y); }
    }
    __syncthreads();
    if (t == 0) {
      int a = 0, bb = 0, hasM = 0;
      if (nL > 0 && nR > 0) {
        int gstartR = (int)regS[pb];
        int gendR   = (int)regS[b + (2 << lvl)];
        int stL; float SYL; LRECC(0, stL, SYL);
        int sb0; float SYR; RRECC(0, sb0, SYR); (void)sb0;
        int eR;
        if (nR > 1) { int nx; RSTC(1, nx); eR = nx - 1; } else eR = gendR - 1;
        float SWL = wsumf(stL, gstartR - 1);
        float SWR = wsumf(gstartR, eR);
        if (SYL * SWR <= SYR * SWL) {
          hasM = 1;
          float SYM = SYL + SYR; int Ms = stL, Me = eR;
          a = 1; bb = 1;
          for (;;) {
            float SWM = wsumf(Ms, Me);
            if (a < nL) {
              int ste; float SYe; LRECC(a, ste, SYe);
              float SWe = wsumf(ste, Ms - 1);
              if (SYe * SWM <= SYM * SWe) { SYM += SYe; Ms = ste; ++a; continue; }
            }
            if (bb < nR) {
              int sb; float SYb; RRECC(bb, sb, SYb);
              int eb;
              if (bb + 1 < nR) { int nx; RSTC(bb + 1, nx); eb = nx - 1; } else eb = gendR - 1;
              float SWb = wsumf(sb, eb);
              if (SYM * SWb <= SYb * SWM) { SYM += SYb; Me = eb; ++bb; continue; }
            }
            break;
          }
          REC[slotL + nL - a] = make_int2(Ms, __float_as_int(SYM));
        }
      }
      shInt[1] = a; shInt[2] = bb; shInt[3] = hasM;
    }
    __syncthreads();
    int a = shInt[1], bb = shInt[2], hasM = shInt[3];
    int destBase = slotL + nL - a + hasM;
    int srcBase = slotR + bb;
    int ncopy = nR - bb;
    if (destBase != srcBase) {
      // register-batched: 2048/stage, read-all -> barrier -> write-all.
      // cross-stage safe: destBase <= srcBase so stage-k writes end below stage-k+1 reads.
      for (int off = 0; off < ncopy; off += 2048) {
        int2 v[8];
#pragma unroll
        for (int j = 0; j < 8; ++j) {
          int k2 = off + j * 256 + t;
          if (k2 < ncopy) v[j] = REC[srcBase + k2];
        }
        __syncthreads();
#pragma unroll
        for (int j = 0; j < 8; ++j) {
          int k2 = off + j * 256 + t;
          if (k2 < ncopy) REC[destBase + k2] = v[j];
        }
        __syncthreads();
      }
    }
    __syncthreads();
    myCnt = nL - a + hasM + (nR - bb);
    ++lvl;
  }
#undef LRECC
#undef RRECC
#undef RSTC
  // ---- out phase: wait for root (load-only poll on one shared line), then 2048 items/block ----
  if (t == 0) {
    u64 f;
    do { f = agent_ld(&flag2[0]); __builtin_amdgcn_s_sleep(2); } while ((f >> 32) != 2ull);
    shInt[0] = (int)(u32)f;
  }
  __syncthreads();
  __threadfence();                         // acquire final REC + all cdf writes
  int m = shInt[0];
  bool useL = (m <= CH_PER_BLK * PAD);
  if (useL) {                              // stage final record table into LDS
    for (int k = t; k < m; k += 256) {
      int2 r = REC[k];
      rST[k] = r.x; rSY[k] = __int_as_float(r.y);
    }
  }
  __syncthreads();
  u32 kmin = ~agg[0], kmax = agg[1];
  float smax = key_to_score(kmin);
  for (int q = 0; q < 8; ++q) {
    int i = b * 2048 + q * 256 + t;
    u32 key = keyRaw[i];
    u32 g = bucket_of(key, kmin, kmax);
    int p = (int)cdf[g];                   // bucket-aligned position of bucket start
    int lo = 0, hi = m - 1;
    if (useL) {
      while (lo < hi) {
        int mid = (lo + hi + 1) >> 1;
        if (rST[mid] <= p) lo = mid; else hi = mid - 1;
      }
      int s0 = rST[lo];
      int e0 = (lo + 1 < m) ? (rST[lo + 1] - 1) : (N_ITEMS - 1);
      float SW = wsumf(s0, e0);
      float sc = key_to_score(key);
      float rank = fexp(sc - smax) * SW / rSY[lo];
      out[i] = floorf(rank * (1.0f / 3.0f)) + 1.0f;
    } else {
      while (lo < hi) {
        int mid = (lo + hi + 1) >> 1;
        if (REC[mid].x <= p) lo = mid; else hi = mid - 1;
      }
      int2 r = REC[lo];
      int s0 = r.x;
      int e0 = (lo + 1 < m) ? (REC[lo + 1].x - 1) : (N_ITEMS - 1);
      float SW = wsumf(s0, e0);
      float sc = key_to_score(key);
      float rank = fexp(sc - smax) * SW / recSY(r);
      out[i] = floorf(rank * (1.0f / 3.0f)) + 1.0f;
    }
  }
}

// ---------- launch ----------

extern "C" void kernel_launch(void* const* d_in, const int* in_sizes, int n_in,
                              void* d_out, int out_size, void* d_ws, size_t ws_size,
                              hipStream_t stream) {
  const float* x  = (const float*)d_in[0];
  const float* w1 = (const float*)d_in[1];
  const float* b1 = (const float*)d_in[2];
  const float* w2 = (const float*)d_in[3];
  const float* b2 = (const float*)d_in[4];
  float* out = (float*)d_out;

  char* ws = (char*)d_ws;
  size_t o = 0;
  u32* cdf    = (u32*)(ws + o); o += (size_t)(NB + 4) * 4;
  u32* keyRaw = (u32*)(ws + o); o += (size_t)N_ITEMS * 4;
  int2* REC   = (int2*)(ws + o); o += (size_t)N_ITEMS * 8;
  u64* hist8  = (u64*)(ws + o); o += (size_t)NSLICE * NB * 8;    // 4 MB, zeroed in-kernel
  // ---- zero-initialized control region (one small memset: 16.5 KB) ----
  char* zbase = ws + o;
  u64* flags  = (u64*)(ws + o); o += (size_t)MBLK * FPAD * 8;    // padded: 128B/slot
  u64* flag2  = (u64*)(ws + o); o += (size_t)MBLK * FPAD * 8;
  u32* agg    = (u32*)(ws + o); o += 64;
  size_t zbytes = (size_t)((ws + o) - zbase);

  hipMemsetAsync(zbase, 0, zbytes, stream);
  score_key_kernel<<<512, 256, 0, stream>>>(x, w1, b1, w2, b2, keyRaw, agg, hist8);
  hist_kernel<<<512, 256, 0, stream>>>(keyRaw, agg, hist8);
  solve_kernel<<<MBLK, 256, 0, stream>>>(hist8, flags, flag2, cdf, REC, keyRaw, agg, out);
}